// Round 1
// baseline (207.593 us; speedup 1.0000x reference)
//
#include <hip/hip_runtime.h>
#include <math.h>

#define NQ 512
#define NC 8000
#define DNUM 6
#define NBINS 50
#define DBIN 300     // DNUM * NBINS
#define DCAT 20
#define DTOT 320     // DBIN + DCAT
#define DOUT 10
#define CHUNK 1000
#define NCHUNK 8
#define QT 16

// ---------- encode candidates, transposed: cT[d][c], d in [0,320), c in [0,8000) ----------
__global__ void enc_cand(const float* __restrict__ xn, const float* __restrict__ xc,
                         const float* __restrict__ delta, const float* __restrict__ u,
                         float* __restrict__ cT) {
    int c = blockIdx.x * 256 + threadIdx.x;
    int d = blockIdx.y;
    if (c >= NC) return;
    float v;
    if (d < DBIN) {
        int f = d / NBINS;
        // exact reference op order: scaled_u = u*delta; ceil((x - scaled_u)/delta)
        float dl = delta[d];
        float sc = u[d] * dl;
        v = ceilf((xn[c * DNUM + f] - sc) / dl);
    } else {
        v = xc[c * DCAT + (d - DBIN)];
    }
    cT[(size_t)d * NC + c] = v;
}

// ---------- encode queries, transposed: xT[d][q] ----------
__global__ void enc_query(const float* __restrict__ xn, const float* __restrict__ xc,
                          const float* __restrict__ delta, const float* __restrict__ u,
                          float* __restrict__ xT) {
    int q = blockIdx.x * 256 + threadIdx.x;
    int d = blockIdx.y;
    if (q >= NQ) return;
    float v;
    if (d < DBIN) {
        int f = d / NBINS;
        float dl = delta[d];
        float sc = u[d] * dl;
        v = ceilf((xn[q * DNUM + f] - sc) / dl);
    } else {
        v = xc[q * DCAT + (d - DBIN)];
    }
    xT[(size_t)d * NQ + q] = v;
}

// ---------- main: block = (16-query tile, one 1000-candidate chunk) ----------
__global__ __launch_bounds__(512) void nca_main(
    const float* __restrict__ cT, const float* __restrict__ xT,
    const int* __restrict__ cy,
    float* __restrict__ g_logits, float* __restrict__ g_lse) {
    __shared__ float xs[DTOT * QT];        // 20 KB, xs[d*16+q]
    __shared__ float lds_logits[QT * DOUT];
    __shared__ float wred[QT * 8];
    __shared__ float m_sh[QT];

    const int tid = threadIdx.x;
    const int q0 = blockIdx.x * QT;
    const int chunk = blockIdx.y;

    for (int i = tid; i < DTOT * QT; i += 512) {
        int d = i >> 4, q = i & (QT - 1);
        xs[i] = xT[d * NQ + q0 + q];
    }
    if (tid < QT * DOUT) lds_logits[tid] = 0.f;
    __syncthreads();

    const bool active = (tid < 500);           // 500 threads * 2 candidates = 1000 exactly
    const int cl = active ? (2 * tid) : 998;   // clamp inactive lanes to a safe address
    const float* cp = cT + chunk * CHUNK + cl;

    float2 acc[QT];
#pragma unroll
    for (int q = 0; q < QT; ++q) acc[q] = make_float2(0.f, 0.f);

#pragma unroll 2
    for (int d = 0; d < DTOT; ++d) {
        float2 cv = *(const float2*)(cp + (size_t)d * NC);
        const float* xv = xs + d * QT;
#pragma unroll
        for (int q = 0; q < QT; ++q) {
            float xq = xv[q];
            acc[q].x += fabsf(cv.x - xq);
            acc[q].y += fabsf(cv.y - xq);
        }
    }

    // ---- logits: sum exp(-dist) per class via LDS atomics ----
    if (active) {
        int2 yv = *(const int2*)(cy + chunk * CHUNK + cl);
#pragma unroll
        for (int q = 0; q < QT; ++q) {
            atomicAdd(&lds_logits[q * DOUT + yv.x], __expf(-acc[q].x));
            atomicAdd(&lds_logits[q * DOUT + yv.y], __expf(-acc[q].y));
        }
    }

    const int lane = tid & 63, wave = tid >> 6;

    // ---- per-q chunk min(dist) ----
#pragma unroll
    for (int q = 0; q < QT; ++q) {
        float v = active ? fminf(acc[q].x, acc[q].y) : INFINITY;
#pragma unroll
        for (int m = 32; m >= 1; m >>= 1) v = fminf(v, __shfl_xor(v, m));
        if (lane == 0) wred[q * 8 + wave] = v;
    }
    __syncthreads();
    if (tid < QT) {
        float m = wred[tid * 8];
#pragma unroll
        for (int w = 1; w < 8; ++w) m = fminf(m, wred[tid * 8 + w]);
        m_sh[tid] = m;
    }
    __syncthreads();

    // ---- stable sum: sum exp(m - dist) ----
#pragma unroll
    for (int q = 0; q < QT; ++q) {
        float m = m_sh[q];
        float s = active ? (__expf(m - acc[q].x) + __expf(m - acc[q].y)) : 0.f;
#pragma unroll
        for (int mm = 32; mm >= 1; mm >>= 1) s += __shfl_xor(s, mm);
        if (lane == 0) wred[q * 8 + wave] = s;
    }
    __syncthreads();
    if (tid < QT) {
        float s = 0.f;
#pragma unroll
        for (int w = 0; w < 8; ++w) s += wred[tid * 8 + w];
        // lse_chunk = log(sum_c exp(-dist)) = log(sum exp(m - dist)) - m
        atomicAdd(&g_lse[q0 + tid], logf(s) - m_sh[tid]);
    }
    __syncthreads();
    if (tid < QT * DOUT) {
        atomicAdd(&g_logits[q0 * DOUT + tid], lds_logits[tid]);
    }
}

// ---------- finalize ----------
__global__ void finalize(const float* __restrict__ g_logits, const float* __restrict__ g_lse,
                         float* __restrict__ out) {
    int i = blockIdx.x * 256 + threadIdx.x;
    if (i < NQ * DOUT) out[i] = logf(g_logits[i] + 1e-8f) - g_lse[i / DOUT];
}

extern "C" void kernel_launch(void* const* d_in, const int* in_sizes, int n_in,
                              void* d_out, int out_size, void* d_ws, size_t ws_size,
                              hipStream_t stream) {
    const float* x_num = (const float*)d_in[0];
    const float* x_cat = (const float*)d_in[1];
    const float* c_num = (const float*)d_in[2];
    const float* c_cat = (const float*)d_in[3];
    const int*   c_y   = (const int*)d_in[4];
    const float* delta = (const float*)d_in[5];
    const float* u     = (const float*)d_in[6];

    float* ws = (float*)d_ws;
    float* cT = ws;                               // 320*8000 = 2,560,000 floats
    float* xT = cT + (size_t)DTOT * NC;           // 320*512  = 163,840
    float* g_logits = xT + (size_t)DTOT * NQ;     // 5120
    float* g_lse = g_logits + NQ * DOUT;          // 512

    hipMemsetAsync(g_logits, 0, (NQ * DOUT + NQ) * sizeof(float), stream);
    enc_cand<<<dim3((NC + 255) / 256, DTOT), 256, 0, stream>>>(c_num, c_cat, delta, u, cT);
    enc_query<<<dim3((NQ + 255) / 256, DTOT), 256, 0, stream>>>(x_num, x_cat, delta, u, xT);
    nca_main<<<dim3(NQ / QT, NCHUNK), 512, 0, stream>>>(cT, xT, c_y, g_logits, g_lse);
    finalize<<<(NQ * DOUT + 255) / 256, 256, 0, stream>>>(g_logits, g_lse, (float*)d_out);
}

// Round 2
// 205.889 us; speedup vs baseline: 1.0083x; 1.0083x over previous
//
#include <hip/hip_runtime.h>
#include <math.h>

#define NQ 512
#define NC 8000
#define DNUM 6
#define NBINS 50
#define DBIN 300     // DNUM * NBINS
#define DCAT 20
#define DTOT 320     // DBIN + DCAT
#define DOUT 10
#define CHUNK 1000
#define NCHUNK 8
#define QT 8

// ---------- encode candidates + queries, transposed: cT[d][c], xT[d][q] ----------
__global__ void enc_all(const float* __restrict__ c_num, const float* __restrict__ c_cat,
                        const float* __restrict__ x_num, const float* __restrict__ x_cat,
                        const float* __restrict__ delta, const float* __restrict__ u,
                        float* __restrict__ cT, float* __restrict__ xT) {
    int r = blockIdx.x * 256 + threadIdx.x;   // 0..8511 : first 8000 candidates, then 512 queries
    int d = blockIdx.y;
    if (r >= NC + NQ) return;
    const bool is_cand = (r < NC);
    const int idx = is_cand ? r : (r - NC);
    const float* xn = is_cand ? c_num : x_num;
    const float* xc = is_cand ? c_cat : x_cat;
    float v;
    if (d < DBIN) {
        int f = d / NBINS;
        // exact reference op order: scaled_u = u*delta; ceil((x - scaled_u)/delta)
        float dl = delta[d];
        float sc = u[d] * dl;
        v = ceilf((xn[idx * DNUM + f] - sc) / dl);
    } else {
        v = xc[idx * DCAT + (d - DBIN)];
    }
    if (is_cand) cT[(size_t)d * NC + idx] = v;
    else         xT[(size_t)d * NQ + idx] = v;
}

// ---------- main: block = (8-query tile, one 1000-candidate chunk) ----------
// grid = (NCHUNK, NQ/QT): chunk on blockIdx.x so all blocks sharing a chunk's
// cT slice map to the same XCD (linear id % 8 == chunk) for L2 locality.
__global__ __launch_bounds__(512) void nca_main(
    const float* __restrict__ cT, const float* __restrict__ xT,
    const int* __restrict__ cy,
    float* __restrict__ g_logits, float* __restrict__ g_lse) {
    __shared__ float lds_logits[QT * DOUT];   // 80 floats
    __shared__ float wred[QT * 8];
    __shared__ float m_sh[QT];

    const int tid = threadIdx.x;
    const int chunk = blockIdx.x;
    const int q0 = blockIdx.y * QT;

    if (tid < QT * DOUT) lds_logits[tid] = 0.f;
    __syncthreads();

    const bool active = (tid < 500);           // 500 threads * 2 candidates = 1000 exactly
    const int cl = active ? (2 * tid) : 998;   // clamp inactive lanes to a safe address
    const float* cp = cT + chunk * CHUNK + cl;

    float2 acc[QT];
#pragma unroll
    for (int q = 0; q < QT; ++q) acc[q] = make_float2(0.f, 0.f);

#pragma unroll 4
    for (int d = 0; d < DTOT; ++d) {
        float2 cv = *(const float2*)(cp + (size_t)d * NC);
        // wave-uniform address -> scalar (SMEM) loads, no LDS traffic
        const float* xrow = xT + (size_t)d * NQ + q0;
#pragma unroll
        for (int q = 0; q < QT; ++q) {
            float xq = xrow[q];
            acc[q].x += fabsf(cv.x - xq);
            acc[q].y += fabsf(cv.y - xq);
        }
    }

    // ---- logits: sum exp(-dist) per class via LDS atomics ----
    if (active) {
        int2 yv = *(const int2*)(cy + chunk * CHUNK + cl);
#pragma unroll
        for (int q = 0; q < QT; ++q) {
            atomicAdd(&lds_logits[q * DOUT + yv.x], __expf(-acc[q].x));
            atomicAdd(&lds_logits[q * DOUT + yv.y], __expf(-acc[q].y));
        }
    }

    const int lane = tid & 63, wave = tid >> 6;

    // ---- per-q chunk min(dist) ----
#pragma unroll
    for (int q = 0; q < QT; ++q) {
        float v = active ? fminf(acc[q].x, acc[q].y) : INFINITY;
#pragma unroll
        for (int m = 32; m >= 1; m >>= 1) v = fminf(v, __shfl_xor(v, m));
        if (lane == 0) wred[q * 8 + wave] = v;
    }
    __syncthreads();
    if (tid < QT) {
        float m = wred[tid * 8];
#pragma unroll
        for (int w = 1; w < 8; ++w) m = fminf(m, wred[tid * 8 + w]);
        m_sh[tid] = m;
    }
    __syncthreads();

    // ---- stable sum: sum exp(m - dist) ----
#pragma unroll
    for (int q = 0; q < QT; ++q) {
        float m = m_sh[q];
        float s = active ? (__expf(m - acc[q].x) + __expf(m - acc[q].y)) : 0.f;
#pragma unroll
        for (int mm = 32; mm >= 1; mm >>= 1) s += __shfl_xor(s, mm);
        if (lane == 0) wred[q * 8 + wave] = s;
    }
    __syncthreads();
    if (tid < QT) {
        float s = 0.f;
#pragma unroll
        for (int w = 0; w < 8; ++w) s += wred[tid * 8 + w];
        // lse_chunk = log(sum_c exp(-dist)) = log(sum exp(m - dist)) - m
        atomicAdd(&g_lse[q0 + tid], logf(s) - m_sh[tid]);
    }
    __syncthreads();
    if (tid < QT * DOUT) {
        atomicAdd(&g_logits[q0 * DOUT + tid], lds_logits[tid]);
    }
}

// ---------- finalize ----------
__global__ void finalize(const float* __restrict__ g_logits, const float* __restrict__ g_lse,
                         float* __restrict__ out) {
    int i = blockIdx.x * 256 + threadIdx.x;
    if (i < NQ * DOUT) out[i] = logf(g_logits[i] + 1e-8f) - g_lse[i / DOUT];
}

extern "C" void kernel_launch(void* const* d_in, const int* in_sizes, int n_in,
                              void* d_out, int out_size, void* d_ws, size_t ws_size,
                              hipStream_t stream) {
    const float* x_num = (const float*)d_in[0];
    const float* x_cat = (const float*)d_in[1];
    const float* c_num = (const float*)d_in[2];
    const float* c_cat = (const float*)d_in[3];
    const int*   c_y   = (const int*)d_in[4];
    const float* delta = (const float*)d_in[5];
    const float* u     = (const float*)d_in[6];

    float* ws = (float*)d_ws;
    float* cT = ws;                               // 320*8000 = 2,560,000 floats
    float* xT = cT + (size_t)DTOT * NC;           // 320*512  = 163,840
    float* g_logits = xT + (size_t)DTOT * NQ;     // 5120
    float* g_lse = g_logits + NQ * DOUT;          // 512

    hipMemsetAsync(g_logits, 0, (NQ * DOUT + NQ) * sizeof(float), stream);
    enc_all<<<dim3((NC + NQ + 255) / 256, DTOT), 256, 0, stream>>>(
        c_num, c_cat, x_num, x_cat, delta, u, cT, xT);
    nca_main<<<dim3(NCHUNK, NQ / QT), 512, 0, stream>>>(cT, xT, c_y, g_logits, g_lse);
    finalize<<<(NQ * DOUT + 255) / 256, 256, 0, stream>>>(g_logits, g_lse, (float*)d_out);
}

// Round 3
// 105.995 us; speedup vs baseline: 1.9585x; 1.9424x over previous
//
#include <hip/hip_runtime.h>
#include <math.h>

#define NQ 512
#define NC 8000
#define DNUM 6
#define NBINS 50
#define DCAT 20
#define DENC 26      // DNUM + DCAT
#define DOUT 10
#define CHUNK 1000
#define NCHUNK 8
#define QT 8
#define CPT 4

// ---------- encode ----------
// G_f(v) = sum_j ceil((v - u_fj*delta_fj)/delta_fj). Each per-bin map is
// fp-monotone in v (sub, div-by-positive, ceil), so all 50 bin diffs for a
// feature share sign => sum_j |bin_j(x)-bin_j(c)| == |G_f(x)-G_f(c)| exactly
// (integer-valued floats, sums << 2^24). 320-dim L1 -> 26-dim L1.
// Also transposes cat features and zeroes the logits/lse accumulators.
__global__ void encode(const float* __restrict__ c_num, const float* __restrict__ c_cat,
                       const float* __restrict__ x_num, const float* __restrict__ x_cat,
                       const float* __restrict__ delta, const float* __restrict__ u,
                       float* __restrict__ cEnc, float* __restrict__ qEnc,
                       float* __restrict__ g_acc /* logits(5120) then lse(512) */) {
    int i = blockIdx.x * 256 + threadIdx.x;
    const int nA = (NC + NQ) * DNUM;          // 51072
    const int nB = (NC + NQ) * DCAT;          // 170240
    if (i < nA) {
        int f = i % DNUM, p = i / DNUM;
        bool is_c = p < NC;
        int idx = is_c ? p : p - NC;
        float v = (is_c ? c_num : x_num)[idx * DNUM + f];
        float g = 0.f;
        for (int j = 0; j < NBINS; ++j) {
            // exact reference op order: scaled_u = u*delta; ceil((v - scaled_u)/delta)
            float dl = delta[f * NBINS + j];
            float sc = u[f * NBINS + j] * dl;
            g += ceilf((v - sc) / dl);
        }
        if (is_c) cEnc[f * NC + idx] = g;
        else      qEnc[f * NQ + idx] = g;
    } else if (i < nA + nB) {
        int i2 = i - nA;
        int k = i2 % DCAT, p = i2 / DCAT;
        bool is_c = p < NC;
        int idx = is_c ? p : p - NC;
        float v = (is_c ? c_cat : x_cat)[idx * DCAT + k];
        if (is_c) cEnc[(DNUM + k) * NC + idx] = v;
        else      qEnc[(DNUM + k) * NQ + idx] = v;
    } else {
        int i3 = i - nA - nB;
        if (i3 < NQ * DOUT + NQ) g_acc[i3] = 0.f;
    }
}

// ---------- main: block = (8-query tile, one chunk), 250 threads x 4 cands ----------
__global__ __launch_bounds__(256) void nca_main(
    const float* __restrict__ cEnc, const float* __restrict__ qEnc,
    const int* __restrict__ cy,
    float* __restrict__ g_logits, float* __restrict__ g_lse) {
    __shared__ float lds_logits[QT * DOUT];   // 80 floats
    __shared__ float wred[QT * 4];
    __shared__ float m_sh[QT];

    const int tid = threadIdx.x;
    const int chunk = blockIdx.x;
    const int q0 = blockIdx.y * QT;

    if (tid < QT * DOUT) lds_logits[tid] = 0.f;
    __syncthreads();

    const bool active = (tid < 250);            // 250 threads * 4 candidates = 1000
    const int cl = active ? (4 * tid) : 996;    // clamp inactive lanes to safe addr
    const float* cp = cEnc + chunk * CHUNK + cl;

    float4 acc[QT];
#pragma unroll
    for (int q = 0; q < QT; ++q) acc[q] = make_float4(0.f, 0.f, 0.f, 0.f);

#pragma unroll
    for (int d = 0; d < DENC; ++d) {
        float4 cv = *(const float4*)(cp + (size_t)d * NC);
        const float* qrow = qEnc + (size_t)d * NQ + q0;   // wave-uniform -> scalar loads
#pragma unroll
        for (int q = 0; q < QT; ++q) {
            float xq = qrow[q];
            acc[q].x += fabsf(cv.x - xq);
            acc[q].y += fabsf(cv.y - xq);
            acc[q].z += fabsf(cv.z - xq);
            acc[q].w += fabsf(cv.w - xq);
        }
    }

    // ---- logits: sum exp(-dist) per class via LDS atomics ----
    if (active) {
        int4 yv = *(const int4*)(cy + chunk * CHUNK + cl);
#pragma unroll
        for (int q = 0; q < QT; ++q) {
            atomicAdd(&lds_logits[q * DOUT + yv.x], __expf(-acc[q].x));
            atomicAdd(&lds_logits[q * DOUT + yv.y], __expf(-acc[q].y));
            atomicAdd(&lds_logits[q * DOUT + yv.z], __expf(-acc[q].z));
            atomicAdd(&lds_logits[q * DOUT + yv.w], __expf(-acc[q].w));
        }
    }

    const int lane = tid & 63, wave = tid >> 6;

    // ---- per-q chunk min(dist) ----
#pragma unroll
    for (int q = 0; q < QT; ++q) {
        float v = active ? fminf(fminf(acc[q].x, acc[q].y), fminf(acc[q].z, acc[q].w))
                         : INFINITY;
#pragma unroll
        for (int m = 32; m >= 1; m >>= 1) v = fminf(v, __shfl_xor(v, m));
        if (lane == 0) wred[q * 4 + wave] = v;
    }
    __syncthreads();
    if (tid < QT) {
        float m = wred[tid * 4];
#pragma unroll
        for (int w = 1; w < 4; ++w) m = fminf(m, wred[tid * 4 + w]);
        m_sh[tid] = m;
    }
    __syncthreads();

    // ---- stable sum: sum exp(m - dist) ----
#pragma unroll
    for (int q = 0; q < QT; ++q) {
        float m = m_sh[q];
        float s = active ? (__expf(m - acc[q].x) + __expf(m - acc[q].y) +
                            __expf(m - acc[q].z) + __expf(m - acc[q].w))
                         : 0.f;
#pragma unroll
        for (int mm = 32; mm >= 1; mm >>= 1) s += __shfl_xor(s, mm);
        if (lane == 0) wred[q * 4 + wave] = s;
    }
    __syncthreads();
    if (tid < QT) {
        float s = 0.f;
#pragma unroll
        for (int w = 0; w < 4; ++w) s += wred[tid * 4 + w];
        // lse_chunk = log(sum exp(m - dist)) - m
        atomicAdd(&g_lse[q0 + tid], logf(s) - m_sh[tid]);
    }
    __syncthreads();
    if (tid < QT * DOUT) {
        atomicAdd(&g_logits[q0 * DOUT + tid], lds_logits[tid]);
    }
}

// ---------- finalize ----------
__global__ void finalize(const float* __restrict__ g_logits, const float* __restrict__ g_lse,
                         float* __restrict__ out) {
    int i = blockIdx.x * 256 + threadIdx.x;
    if (i < NQ * DOUT) out[i] = logf(g_logits[i] + 1e-8f) - g_lse[i / DOUT];
}

extern "C" void kernel_launch(void* const* d_in, const int* in_sizes, int n_in,
                              void* d_out, int out_size, void* d_ws, size_t ws_size,
                              hipStream_t stream) {
    const float* x_num = (const float*)d_in[0];
    const float* x_cat = (const float*)d_in[1];
    const float* c_num = (const float*)d_in[2];
    const float* c_cat = (const float*)d_in[3];
    const int*   c_y   = (const int*)d_in[4];
    const float* delta = (const float*)d_in[5];
    const float* u     = (const float*)d_in[6];

    float* ws = (float*)d_ws;
    float* cEnc = ws;                             // 26*8000 = 208,000 floats
    float* qEnc = cEnc + (size_t)DENC * NC;       // 26*512  = 13,312
    float* g_logits = qEnc + (size_t)DENC * NQ;   // 5120
    float* g_lse = g_logits + NQ * DOUT;          // 512 (contiguous after logits)

    const int total = (NC + NQ) * (DNUM + DCAT) + NQ * DOUT + NQ;  // 226,944
    encode<<<(total + 255) / 256, 256, 0, stream>>>(
        c_num, c_cat, x_num, x_cat, delta, u, cEnc, qEnc, g_logits);
    nca_main<<<dim3(NCHUNK, NQ / QT), 256, 0, stream>>>(cEnc, qEnc, c_y, g_logits, g_lse);
    finalize<<<(NQ * DOUT + 255) / 256, 256, 0, stream>>>(g_logits, g_lse, (float*)d_out);
}